// Round 1
// 302.551 us; speedup vs baseline: 1.0936x; 1.0936x over previous
//
#include <hip/hip_runtime.h>
#include <hip/hip_bf16.h>

// Fused Conv3d(3->16,k=3,valid) + conv_b + ReLU + maxpool2x2x2
// + spatial mean(fp32) + /2 + bias + channel-sum  ->  out[32] fp32.
// Inputs are FLOAT32 (harness materializes reference fp16 as f32).
//
// R10: LDS-pipe diet on top of R9's persistent blocks + 32x32x16 MFMA.
//  - K-order is ci-fast: k-slot = dl*4 + ci (ci=3 is the zero pad), so each
//    thread stages one row as ONE ds_write_b64 (2x v_cvt_pk_bf16_f32), not
//    12 scalar b16 writes. Pad is written inline; no pre-zero pass.
//  - Thread map (w4, dr=(tid>>5)&3, hr=(tid>>7)&3): dr&1 differs across wave
//    halves so each b64 write covers all 32 banks (4-cycle floor).
//  - N-column remap col = 2*wi + hh: both pool partners (hh, w-pair) live in
//    the same quad -> v_mov_dpp quad_perm + v_max, zero DS traffic (was 2x
//    ds_bpermute per r).
//  - Double-buffered LDS (2 x 16640 B), ONE __syncthreads per dp iteration.
//  LDS rawT[buf][row=w 0..129][tap = hl*16 + dl*4 + ci] bf16, 128 B/row,
//  16B chunks XOR-swizzled by (row^(row>>3))&7. Rows 128/129 zeroed once.
//  MFMA m32n32k16: M=(dd,ch), N=(wi,hh) cols, K=(dl,ci) per kh-chunk,
//  kw via row-shifted B; 9 MFMAs/wave/iter, ONE acc (kh,kw are conv sums).
//  D (m74/m101): col=lane&31, row=(reg&3)+8*(reg>>2)+4*(lane>>5).
//  Pool: dd = acc[r] vs acc[r+8] (in-reg), hh = DPP 0xB1, w-pair = DPP 0x4E.

typedef __attribute__((ext_vector_type(8)))  short  short8;
typedef __attribute__((ext_vector_type(4)))  float  floatx4;
typedef __attribute__((ext_vector_type(16))) float  floatx16;

__device__ __forceinline__ short f2bf(float f) {
    unsigned u = __builtin_bit_cast(unsigned, f);
    unsigned r = (u + 0x7FFFu + ((u >> 16) & 1u)) >> 16;
    return (short)r;
}

__device__ __forceinline__ unsigned pkbf2(float a, float b) {
    __hip_bfloat162 h = __float22bfloat162_rn(float2{a, b});  // v_cvt_pk_bf16_f32
    unsigned r;
    __builtin_memcpy(&r, &h, 4);
    return r;
}

template <int CTRL>
__device__ __forceinline__ float dpp_max(float v) {
    int x = __builtin_bit_cast(int, v);
    int y = __builtin_amdgcn_mov_dpp(x, CTRL, 0xF, 0xF, true);
    return fmaxf(v, __builtin_bit_cast(float, y));
}

// ---- init: wtab[f=kh*3+kw][lane][8] zero-padded A-frags + out = bias sums ----
__global__ void init_kernel(const float* __restrict__ wg,
                            const float* __restrict__ biasg,
                            short* __restrict__ wtab,   // d_ws: 9*64*8 bf16 = 9216 B
                            float* __restrict__ out)    // [32]
{
    const int t = threadIdx.x;               // 0..575
    if (t < 576) {
        const int lane = t & 63, f = t >> 6;
        const int kh = f / 3, kw = f % 3;
        const int m = lane & 31, hs = lane >> 5;
        const int dd = m >> 4, ch = m & 15;
        short8 v;
        #pragma unroll
        for (int j = 0; j < 8; ++j) {
            const int s = hs * 8 + j;        // k-slot: dl = s>>2, ci = s&3 (ci-fast!)
            const int dl = s >> 2, ci = s & 3;
            const int kd = dl - dd;
            v[j] = (ci < 3 && kd >= 0 && kd < 3)
                 ? f2bf(wg[ch * 81 + ci * 27 + kd * 9 + kh * 3 + kw]) : (short)0;
        }
        ((short8*)wtab)[f * 64 + lane] = v;
    }
    if (t < 32) {
        float s = 0.f;
        #pragma unroll
        for (int cc = 0; cc < 16; ++cc) s += biasg[cc];
        out[t] = s;   // conv blocks atomicAdd on top
    }
}

__global__ __launch_bounds__(512, 4) void fused_conv_pool_reduce(
    const float* __restrict__ xg,    // f32 [32][3][32][128][128]
    const short* __restrict__ wtab,  // bf16 frag table in d_ws
    const float* __restrict__ cbg,   // f32 [16]
    float* __restrict__ out)         // f32 [32]
{
    __shared__ __align__(16) short rawT[2 * 130 * 64];  // 33,280 B (double buffer)
    __shared__ float wsums[8];

    const int hp  = blockIdx.x;   // 0..62
    const int b   = blockIdx.y;   // 0..31
    const int tid = threadIdx.x;  // 0..511
    const int lane = tid & 63;
    const int wv   = tid >> 6;    // wave = 16-wide w tile
    const int hs   = lane >> 5;

    // ---- resident A-frags (36 VGPR) and conv-bias values ----
    short8 af[9];
    #pragma unroll
    for (int f = 0; f < 9; ++f) af[f] = ((const short8*)wtab)[f * 64 + lane];
    float cb8[8];
    #pragma unroll
    for (int r = 0; r < 8; ++r) cb8[r] = cbg[(r & 3) + 8 * (r >> 2) + 4 * hs];

    // ---- zero rows 128/129 of both buffers (once) ----
    if (tid < 64)
        *(unsigned long long*)((char*)rawT + (tid >> 5) * 16640 + 16384 + (tid & 31) * 8) = 0ULL;

    // ---- dp-invariant addresses ----
    // stage map: w4 = tid&31, dr = (tid>>5)&3 (varies ACROSS wave halves -> dr&1
    // alternates per half, full 32-bank coverage per b64 write), hr = (tid>>7)&3.
    const int w4 = tid & 31, dr = (tid >> 5) & 3, hr = (tid >> 7) & 3;
    int waddr[4];
    {
        const int chunkL = hr * 2 + (dr >> 1);
        #pragma unroll
        for (int i = 0; i < 4; ++i) {
            const int row = 4 * w4 + i;
            const int phys = chunkL ^ ((row ^ (row >> 3)) & 7);
            waddr[i] = row * 128 + phys * 16 + (dr & 1) * 8;
        }
    }
    // read map: col = 2*wi + hh  (pool partners at lane^1 and lane^2)
    const int wi = (lane >> 1) & 15, hh = lane & 1;
    int raddr[3][3];
    #pragma unroll
    for (int kh = 0; kh < 3; ++kh) {
        #pragma unroll
        for (int kw = 0; kw < 3; ++kw) {
            const int row = wv * 16 + wi + kw;
            const int phys = ((hh + kh) * 2 + hs) ^ ((row ^ (row >> 3)) & 7);
            raddr[kh][kw] = row * 128 + phys * 16;
        }
    }

    // ---- prefetch dp=0 ----
    const float* src = xg + ((size_t)b * 96 + dr) * 16384 + (2 * hp + hr) * 128 + 4 * w4;
    floatx4 c0 = *(const floatx4*)(src);
    floatx4 c1 = *(const floatx4*)(src + 524288);
    floatx4 c2 = *(const floatx4*)(src + 1048576);

    float vsum = 0.f;
    for (int dp = 0; dp < 15; ++dp) {
        const int bofs = (dp & 1) * 16640;
        // stage current cell: 4x { 2x cvt_pk + ds_write_b64 }
        #pragma unroll
        for (int i = 0; i < 4; ++i) {
            uint2 pk;
            pk.x = pkbf2(c0[i], c1[i]);        // [bf(ci0), bf(ci1)]
            pk.y = pkbf2(c2[i], 0.0f);         // [bf(ci2), 0-pad]
            *(uint2*)((char*)rawT + bofs + waddr[i]) = pk;
        }
        // prefetch next cell (overlaps MFMA + barrier)
        if (dp < 14) {
            src += 32768;
            c0 = *(const floatx4*)(src);
            c1 = *(const floatx4*)(src + 524288);
            c2 = *(const floatx4*)(src + 1048576);
        }
        __syncthreads();   // ONE barrier/iter: next stage goes to other buffer

        floatx16 acc = {0.f,0.f,0.f,0.f,0.f,0.f,0.f,0.f,
                        0.f,0.f,0.f,0.f,0.f,0.f,0.f,0.f};
        #pragma unroll
        for (int kh = 0; kh < 3; ++kh) {
            #pragma unroll
            for (int kw = 0; kw < 3; ++kw) {
                const short8 bf = *(const short8*)((char*)rawT + bofs + raddr[kh][kw]);
                acc = __builtin_amdgcn_mfma_f32_32x32x16_bf16(af[kh * 3 + kw], bf, acc, 0, 0, 0);
            }
        }
        // epilogue: dd-pool in-reg, +conv_b, relu, hh-pool (DPP ^1), w-pool (DPP ^2)
        #pragma unroll
        for (int r = 0; r < 8; ++r) {
            float v = fmaxf(fmaxf(acc[r], acc[r + 8]) + cb8[r], 0.f);
            v = dpp_max<0xB1>(v);   // pool over hh   (lane ^ 1, quad_perm [1,0,3,2])
            v = dpp_max<0x4E>(v);   // pool over w pair (lane ^ 2, quad_perm [2,3,0,1])
            vsum += v;
        }
    }

    // valid lanes: quad leaders (hh==0, wi even), pooled pair base <= 124 (conv W=126)
    const bool okl = ((lane & 3) == 0) && (wv * 16 + wi <= 124);
    float s = okl ? vsum : 0.f;
    #pragma unroll
    for (int off = 1; off < 64; off <<= 1) s += __shfl_xor(s, off, 64);

    if (lane == 0) wsums[wv] = s;
    __syncthreads();
    if (tid == 0) {
        float bs = 0.f;
        #pragma unroll
        for (int i = 0; i < 8; ++i) bs += wsums[i];
        atomicAdd(&out[b], bs * (1.0f / 119070.0f));   // /(15*63*63)/2
    }
}

extern "C" void kernel_launch(void* const* d_in, const int* in_sizes, int n_in,
                              void* d_out, int out_size, void* d_ws, size_t ws_size,
                              hipStream_t stream) {
    const float* x      = (const float*)d_in[0];
    const float* conv_w = (const float*)d_in[1];
    const float* conv_b = (const float*)d_in[2];
    const float* bias   = (const float*)d_in[3];
    float* out = (float*)d_out;
    short* wtab = (short*)d_ws;   // 9216 B

    init_kernel<<<1, 576, 0, stream>>>(conv_w, bias, wtab, out);
    dim3 grid(63, 32);  // (hp, b)
    fused_conv_pool_reduce<<<grid, 512, 0, stream>>>(x, wtab, conv_b, out);
}